// Round 1
// baseline (2947.717 us; speedup 1.0000x reference)
//
#include <hip/hip_runtime.h>

// SAGEConv fused: out = h@W_self.T + b_self + b_nb + segsum(val * (h@W_nb.T)[col])
// Restructure: apply W_nb BEFORE aggregation (linearity) -> edge stage is pure
// gather/scale/scatter-add of precomputed rows, no second GEMM pass.

constexpr int NN = 100000;
constexpr int NE = 1600000;
constexpr int D  = 128;

// ---------------- Kernel A: dual GEMM (fp32 vector ALU; no fp32 MFMA on CDNA4)
// Tile 64(M) x 64(N of 256 concat cols), K=128 staged whole. 4x4 micro-tile.
// Pad +1: compute-loop a/b LDS reads land <=2 lanes/bank (free on gfx950).
__global__ __launch_bounds__(256) void gemm_dual(
    const float* __restrict__ h,
    const float* __restrict__ Wself,
    const float* __restrict__ bself,
    const float* __restrict__ Wnb,
    const float* __restrict__ bnb,
    float* __restrict__ out,
    float* __restrict__ tmp)
{
    __shared__ float hs[64][D + 1];   // ~33 KB
    __shared__ float ws[64][D + 1];   // ~33 KB -> 2 blocks/CU, 8 waves/CU
    const int t  = threadIdx.x;
    const int m0 = blockIdx.x * 64;
    const int n0 = blockIdx.y * 64;   // 0,64,128,192 over concat [W_self;W_nb]

    #pragma unroll
    for (int it = 0; it < 8; ++it) {          // stage h tile (coalesced float4)
        int idx = it * 1024 + t * 4;
        int r = idx >> 7, c = idx & 127;
        int gr = m0 + r;
        float4 v = make_float4(0.f, 0.f, 0.f, 0.f);
        if (gr < NN) v = *(const float4*)(h + (size_t)gr * D + c);
        hs[r][c+0] = v.x; hs[r][c+1] = v.y; hs[r][c+2] = v.z; hs[r][c+3] = v.w;
    }
    #pragma unroll
    for (int it = 0; it < 8; ++it) {          // stage W tile (rows = out cols)
        int idx = it * 1024 + t * 4;
        int r = idx >> 7, c = idx & 127;
        int gn = n0 + r;
        const float* Wr = (gn < D) ? (Wself + (size_t)gn * D)
                                   : (Wnb + (size_t)(gn - D) * D);
        float4 v = *(const float4*)(Wr + c);
        ws[r][c+0] = v.x; ws[r][c+1] = v.y; ws[r][c+2] = v.z; ws[r][c+3] = v.w;
    }
    __syncthreads();

    const int tm = (t >> 4) * 4;
    const int tn = (t & 15) * 4;
    float acc[4][4] = {};
    #pragma unroll 4
    for (int k = 0; k < D; ++k) {
        float a[4], b[4];
        #pragma unroll
        for (int i = 0; i < 4; ++i) a[i] = hs[tm + i][k];
        #pragma unroll
        for (int j = 0; j < 4; ++j) b[j] = ws[tn + j][k];
        #pragma unroll
        for (int i = 0; i < 4; ++i)
            #pragma unroll
            for (int j = 0; j < 4; ++j)
                acc[i][j] += a[i] * b[j];
    }

    #pragma unroll
    for (int i = 0; i < 4; ++i) {
        int row = m0 + tm + i;
        if (row >= NN) break;
        #pragma unroll
        for (int j = 0; j < 4; ++j) {
            int col = n0 + tn + j;
            if (col < D) out[(size_t)row * D + col] = acc[i][j] + bself[col] + bnb[col];
            else         tmp[(size_t)row * D + (col - D)] = acc[i][j];
        }
    }
}

// ---------------- Kernel B: edge gather/scale/scatter-add
// 32 lanes per edge, float4 per lane (512 B contiguous gather per edge; tmp is
// 51 MB -> L3-resident). unsafeAtomicAdd -> hw global_atomic_add_f32.
__global__ __launch_bounds__(256) void edge_scatter(
    const float* __restrict__ tmp,
    const float* __restrict__ eval_,
    const int* __restrict__ erow,
    const int* __restrict__ ecol,
    float* __restrict__ out)
{
    int gid = blockIdx.x * 256 + threadIdx.x;
    int e = gid >> 5;
    if (e >= NE) return;
    int lane = gid & 31;
    int r = erow[e];
    int c = ecol[e];
    float v = eval_[e];
    float4 hv = *(const float4*)(tmp + (size_t)c * D + lane * 4);
    float* o = out + (size_t)r * D + lane * 4;
    unsafeAtomicAdd(o + 0, v * hv.x);
    unsafeAtomicAdd(o + 1, v * hv.y);
    unsafeAtomicAdd(o + 2, v * hv.z);
    unsafeAtomicAdd(o + 3, v * hv.w);
}

extern "C" void kernel_launch(void* const* d_in, const int* in_sizes, int n_in,
                              void* d_out, int out_size, void* d_ws, size_t ws_size,
                              hipStream_t stream) {
    const float* h     = (const float*)d_in[0];
    const float* eval_ = (const float*)d_in[1];
    const float* Wself = (const float*)d_in[2];
    const float* bself = (const float*)d_in[3];
    const float* Wnb   = (const float*)d_in[4];
    const float* bnb   = (const float*)d_in[5];
    const int*   erow  = (const int*)d_in[6];
    const int*   ecol  = (const int*)d_in[7];
    float* out = (float*)d_out;
    float* tmp = (float*)d_ws;  // needs 100000*128*4 = 51.2 MB

    dim3 g1((NN + 63) / 64, 4);
    gemm_dual<<<g1, 256, 0, stream>>>(h, Wself, bself, Wnb, bnb, out, tmp);

    int nb = (NE * 32) / 256;   // 200000 blocks, exact
    edge_scatter<<<nb, 256, 0, stream>>>(tmp, eval_, erow, ecol, out);
}

// Round 2
// 711.230 us; speedup vs baseline: 4.1445x; 4.1445x over previous
//
#include <hip/hip_runtime.h>

// SAGEConv: out = h@W_self.T + b_self + b_nb + segsum(val * (h@W_nb.T)[col])
// R2: replace 205M fp32 atomics (atomic-throughput-bound, 3.2GB WRITE_SIZE)
// with on-device CSR build (1.6M int atomics) + per-row gather aggregation.

constexpr int NN = 100000;
constexpr int NE = 1600000;
constexpr int D  = 128;

// ---------------- Kernel A: dual GEMM (fp32 vector ALU; no fp32 MFMA on CDNA4)
__global__ __launch_bounds__(256) void gemm_dual(
    const float* __restrict__ h,
    const float* __restrict__ Wself,
    const float* __restrict__ bself,
    const float* __restrict__ Wnb,
    const float* __restrict__ bnb,
    float* __restrict__ out,
    float* __restrict__ tmp)
{
    __shared__ float hs[64][D + 1];
    __shared__ float ws[64][D + 1];
    const int t  = threadIdx.x;
    const int m0 = blockIdx.x * 64;
    const int n0 = blockIdx.y * 64;   // 0..192 over concat [W_self;W_nb]

    #pragma unroll
    for (int it = 0; it < 8; ++it) {
        int idx = it * 1024 + t * 4;
        int r = idx >> 7, c = idx & 127;
        int gr = m0 + r;
        float4 v = make_float4(0.f, 0.f, 0.f, 0.f);
        if (gr < NN) v = *(const float4*)(h + (size_t)gr * D + c);
        hs[r][c+0] = v.x; hs[r][c+1] = v.y; hs[r][c+2] = v.z; hs[r][c+3] = v.w;
    }
    #pragma unroll
    for (int it = 0; it < 8; ++it) {
        int idx = it * 1024 + t * 4;
        int r = idx >> 7, c = idx & 127;
        int gn = n0 + r;
        const float* Wr = (gn < D) ? (Wself + (size_t)gn * D)
                                   : (Wnb + (size_t)(gn - D) * D);
        float4 v = *(const float4*)(Wr + c);
        ws[r][c+0] = v.x; ws[r][c+1] = v.y; ws[r][c+2] = v.z; ws[r][c+3] = v.w;
    }
    __syncthreads();

    const int tm = (t >> 4) * 4;
    const int tn = (t & 15) * 4;
    float acc[4][4] = {};
    #pragma unroll 4
    for (int k = 0; k < D; ++k) {
        float a[4], b[4];
        #pragma unroll
        for (int i = 0; i < 4; ++i) a[i] = hs[tm + i][k];
        #pragma unroll
        for (int j = 0; j < 4; ++j) b[j] = ws[tn + j][k];
        #pragma unroll
        for (int i = 0; i < 4; ++i)
            #pragma unroll
            for (int j = 0; j < 4; ++j)
                acc[i][j] += a[i] * b[j];
    }

    #pragma unroll
    for (int i = 0; i < 4; ++i) {
        int row = m0 + tm + i;
        if (row >= NN) break;
        #pragma unroll
        for (int j = 0; j < 4; ++j) {
            int col = n0 + tn + j;
            if (col < D) out[(size_t)row * D + col] = acc[i][j] + bself[col] + bnb[col];
            else         tmp[(size_t)row * D + (col - D)] = acc[i][j];
        }
    }
}

// ---------------- CSR build ----------------
__global__ __launch_bounds__(256) void zero_counts(int* __restrict__ counts) {
    int i = blockIdx.x * 256 + threadIdx.x;
    if (i < NN) counts[i] = 0;
}

__global__ __launch_bounds__(256) void histogram(
    const int* __restrict__ erow, int* __restrict__ counts) {
    int e = blockIdx.x * 256 + threadIdx.x;
    if (e < NE) atomicAdd(&counts[erow[e]], 1);
}

// Single-block scan: 1024 threads x 4 elems/chunk = 4096/chunk, 25 chunks.
// Writes exclusive offsets[0..NN] and cursor[i]=offsets[i].
__global__ __launch_bounds__(1024) void scan_offsets(
    const int* __restrict__ counts, int* __restrict__ offsets,
    int* __restrict__ cursor) {
    __shared__ int sdata[1024];
    __shared__ int carry_s;
    const int t = threadIdx.x;
    if (t == 0) carry_s = 0;
    __syncthreads();
    for (int base = 0; base < NN; base += 4096) {
        int idx = base + t * 4;
        int v[4];
        #pragma unroll
        for (int i = 0; i < 4; ++i) {
            int j = idx + i;
            v[i] = (j < NN) ? counts[j] : 0;
        }
        int lsum = v[0] + v[1] + v[2] + v[3];
        sdata[t] = lsum;
        __syncthreads();
        for (int off = 1; off < 1024; off <<= 1) {
            int y = 0;
            if (t >= off) y = sdata[t - off];
            __syncthreads();
            if (t >= off) sdata[t] += y;
            __syncthreads();
        }
        int excl = sdata[t] - lsum + carry_s;
        #pragma unroll
        for (int i = 0; i < 4; ++i) {
            int j = idx + i;
            if (j < NN) { offsets[j] = excl; cursor[j] = excl; excl += v[i]; }
        }
        __syncthreads();
        if (t == 0) carry_s += sdata[1023];
        __syncthreads();
    }
    if (t == 0) offsets[NN] = carry_s;
}

__global__ __launch_bounds__(256) void scatter_csr(
    const int* __restrict__ erow, const int* __restrict__ ecol,
    const float* __restrict__ eval_, int* __restrict__ cursor,
    int* __restrict__ scol, float* __restrict__ sval) {
    int e = blockIdx.x * 256 + threadIdx.x;
    if (e >= NE) return;
    int r = erow[e];
    int pos = atomicAdd(&cursor[r], 1);
    scol[pos] = ecol[e];
    sval[pos] = eval_[e];
}

// ---------------- Aggregate: one 64-lane wave per row, float2 per lane ----
__global__ __launch_bounds__(256) void aggregate(
    const float* __restrict__ tmp, const int* __restrict__ offsets,
    const int* __restrict__ scol, const float* __restrict__ sval,
    float* __restrict__ out) {
    int wave = (blockIdx.x * 256 + threadIdx.x) >> 6;
    if (wave >= NN) return;
    int lane = threadIdx.x & 63;
    int beg = offsets[wave];
    int end = offsets[wave + 1];
    float2 acc = make_float2(0.f, 0.f);
    for (int e = beg; e < end; ++e) {
        int   c = scol[e];
        float v = sval[e];
        float2 tv = *(const float2*)(tmp + (size_t)c * D + lane * 2);
        acc.x += v * tv.x;
        acc.y += v * tv.y;
    }
    float2* o = (float2*)(out + (size_t)wave * D + lane * 2);
    float2 cur = *o;
    cur.x += acc.x; cur.y += acc.y;
    *o = cur;
}

extern "C" void kernel_launch(void* const* d_in, const int* in_sizes, int n_in,
                              void* d_out, int out_size, void* d_ws, size_t ws_size,
                              hipStream_t stream) {
    const float* h     = (const float*)d_in[0];
    const float* eval_ = (const float*)d_in[1];
    const float* Wself = (const float*)d_in[2];
    const float* bself = (const float*)d_in[3];
    const float* Wnb   = (const float*)d_in[4];
    const float* bnb   = (const float*)d_in[5];
    const int*   erow  = (const int*)d_in[6];
    const int*   ecol  = (const int*)d_in[7];
    float* out = (float*)d_out;

    // Workspace layout: tmp(NN*D f32) | counts(NN) | offsets(NN+1) | cursor(NN)
    //                   | scol(NE) | sval(NE)   -> ~65.2 MB total
    float* tmp     = (float*)d_ws;
    int*   counts  = (int*)(tmp + (size_t)NN * D);
    int*   offsets = counts + NN;
    int*   cursor  = offsets + NN + 1;
    int*   scol    = cursor + NN;
    float* sval    = (float*)(scol + NE);

    dim3 g1((NN + 63) / 64, 4);
    gemm_dual<<<g1, 256, 0, stream>>>(h, Wself, bself, Wnb, bnb, out, tmp);

    zero_counts<<<(NN + 255) / 256, 256, 0, stream>>>(counts);
    histogram<<<(NE + 255) / 256, 256, 0, stream>>>(erow, counts);
    scan_offsets<<<1, 1024, 0, stream>>>(counts, offsets, cursor);
    scatter_csr<<<(NE + 255) / 256, 256, 0, stream>>>(erow, ecol, eval_, cursor, scol, sval);
    aggregate<<<(NN * 64 + 255) / 256, 256, 0, stream>>>(tmp, offsets, scol, sval, out);
}

// Round 3
// 466.916 us; speedup vs baseline: 6.3132x; 1.5233x over previous
//
#include <hip/hip_runtime.h>

// SAGEConv: out = h@W_self.T + b_self + b_nb + segsum(val * (h@W_nb.T)[col])
// R3: (a) LDS-free bf16 MFMA dual-GEMM (was 196us fp32 VALU @33TF),
//     (b) tmp stored bf16 -> halves aggregate gather traffic,
//     (c) hierarchical scan, packed int2 edge pairs, memsetAsync for counts.

constexpr int NN = 100000;
constexpr int NE = 1600000;
constexpr int D  = 128;
constexpr int NB = (NN + 255) / 256;       // 391 scan blocks
constexpr int NN_PAD = 100032;             // 64-row padded for GEMM tiles

typedef __bf16 bf16x8 __attribute__((ext_vector_type(8)));
typedef float  f32x4  __attribute__((ext_vector_type(4)));

// ---------------- W concat -> bf16 table wcat[256][128] ----------------
__global__ __launch_bounds__(256) void w_convert(
    const float* __restrict__ Wself, const float* __restrict__ Wnb,
    __bf16* __restrict__ wcat) {
    int i = blockIdx.x * 256 + threadIdx.x;   // 0..32767
    int n = i >> 7, k = i & 127;
    float v = (n < D) ? Wself[(size_t)n * D + k] : Wnb[(size_t)(n - D) * D + k];
    wcat[i] = (__bf16)v;
}

// ---------------- Dual GEMM, LDS-free MFMA ----------------
// Wave owns 16 M-rows; loops 16 N-subtiles (cols 0..255) x 4 K-steps.
// C/D layout (m89): col=lane&15, row=(lane>>4)*4+reg.
// A/B frag: row/col = lane&15, k = (lane>>4)*8 + j.
__global__ __launch_bounds__(256) void gemm_mfma(
    const float* __restrict__ h,
    const __bf16* __restrict__ wcat,
    const float* __restrict__ bself,
    const float* __restrict__ bnb,
    float* __restrict__ out,
    __bf16* __restrict__ tmpb)
{
    const int t    = threadIdx.x;
    const int wv   = t >> 6;
    const int lane = t & 63;
    const int l15  = lane & 15;
    const int quad = lane >> 4;
    const int m0   = blockIdx.x * 64 + wv * 16;

    int arow = m0 + l15;
    if (arow >= NN) arow = NN - 1;            // clamp: keep loads in-bounds
    const float* aptr = h + (size_t)arow * D + quad * 8;

    bf16x8 afr[4];
    #pragma unroll
    for (int kk = 0; kk < 4; ++kk) {          // k0 = 32*kk
        f32x4 lo = *(const f32x4*)(aptr + kk * 32);
        f32x4 hi = *(const f32x4*)(aptr + kk * 32 + 4);
        bf16x8 a;
        #pragma unroll
        for (int j = 0; j < 4; ++j) { a[j] = (__bf16)lo[j]; a[4 + j] = (__bf16)hi[j]; }
        afr[kk] = a;
    }

    f32x4 acc[16];
    #pragma unroll
    for (int ns = 0; ns < 16; ++ns) acc[ns] = (f32x4){0.f, 0.f, 0.f, 0.f};

    #pragma unroll
    for (int ns = 0; ns < 16; ++ns) {
        const __bf16* wr = wcat + (size_t)(ns * 16 + l15) * D + quad * 8;
        #pragma unroll
        for (int kk = 0; kk < 4; ++kk) {
            bf16x8 b = *(const bf16x8*)(wr + kk * 32);
            acc[ns] = __builtin_amdgcn_mfma_f32_16x16x32_bf16(afr[kk], b, acc[ns], 0, 0, 0);
        }
    }

    #pragma unroll
    for (int ns = 0; ns < 16; ++ns) {
        int col = ns * 16 + l15;
        float bias = (col < D) ? (bself[col] + bnb[col]) : 0.f;
        #pragma unroll
        for (int i = 0; i < 4; ++i) {
            int row = m0 + quad * 4 + i;
            if (row < NN) {
                float v = acc[ns][i];
                if (col < D) out[(size_t)row * D + col] = v + bias;
                else         tmpb[(size_t)row * D + (col - D)] = (__bf16)v;
            }
        }
    }
}

// ---------------- CSR build ----------------
__global__ __launch_bounds__(256) void histogram(
    const int* __restrict__ erow, int* __restrict__ counts) {
    int e = blockIdx.x * 256 + threadIdx.x;
    if (e < NE) atomicAdd(&counts[erow[e]], 1);
}

__global__ __launch_bounds__(256) void block_sums(
    const int* __restrict__ counts, int* __restrict__ bsum) {
    __shared__ int s[256];
    int t = threadIdx.x, i = blockIdx.x * 256 + t;
    s[t] = (i < NN) ? counts[i] : 0;
    __syncthreads();
    #pragma unroll
    for (int o = 128; o > 0; o >>= 1) {
        if (t < o) s[t] += s[t + o];
        __syncthreads();
    }
    if (t == 0) bsum[blockIdx.x] = s[0];
}

__global__ __launch_bounds__(512) void scan_bsums(
    const int* __restrict__ bsum, int* __restrict__ bscan,
    int* __restrict__ offsets) {
    __shared__ int s[512];
    int t = threadIdx.x;
    int v = (t < NB) ? bsum[t] : 0;
    s[t] = v;
    __syncthreads();
    for (int o = 1; o < 512; o <<= 1) {
        int y = (t >= o) ? s[t - o] : 0;
        __syncthreads();
        s[t] += y;
        __syncthreads();
    }
    if (t < NB) bscan[t] = s[t] - v;     // exclusive
    if (t == NB - 1) offsets[NN] = s[t]; // total = NE
}

__global__ __launch_bounds__(256) void scan_local(
    const int* __restrict__ counts, const int* __restrict__ bscan,
    int* __restrict__ offsets, int* __restrict__ cursor) {
    __shared__ int s[256];
    int t = threadIdx.x, i = blockIdx.x * 256 + t;
    int v = (i < NN) ? counts[i] : 0;
    s[t] = v;
    __syncthreads();
    for (int o = 1; o < 256; o <<= 1) {
        int y = (t >= o) ? s[t - o] : 0;
        __syncthreads();
        s[t] += y;
        __syncthreads();
    }
    if (i < NN) {
        int excl = s[t] - v + bscan[blockIdx.x];
        offsets[i] = excl;
        cursor[i]  = excl;
    }
}

__global__ __launch_bounds__(256) void scatter_csr(
    const int* __restrict__ erow, const int* __restrict__ ecol,
    const float* __restrict__ eval_, int* __restrict__ cursor,
    int2* __restrict__ epair) {
    int e = blockIdx.x * 256 + threadIdx.x;
    if (e >= NE) return;
    int pos = atomicAdd(&cursor[erow[e]], 1);
    epair[pos] = make_int2(ecol[e], __float_as_int(eval_[e]));
}

// ---------------- Aggregate: one wave per row, bf16 tmp, 2x unroll ------
__global__ __launch_bounds__(256) void aggregate(
    const __bf16* __restrict__ tmpb, const int* __restrict__ offsets,
    const int2* __restrict__ epair, float* __restrict__ out) {
    int wave = (blockIdx.x * 256 + threadIdx.x) >> 6;
    if (wave >= NN) return;
    int lane = threadIdx.x & 63;
    int beg = offsets[wave];
    int end = offsets[wave + 1];
    float ax0 = 0.f, ay0 = 0.f, ax1 = 0.f, ay1 = 0.f;
    int e = beg;
    for (; e + 1 < end; e += 2) {
        int2 p0 = epair[e];
        int2 p1 = epair[e + 1];
        unsigned u0 = *(const unsigned*)(tmpb + (size_t)p0.x * D + lane * 2);
        unsigned u1 = *(const unsigned*)(tmpb + (size_t)p1.x * D + lane * 2);
        float v0 = __int_as_float(p0.y);
        float v1 = __int_as_float(p1.y);
        ax0 += v0 * __uint_as_float(u0 << 16);
        ay0 += v0 * __uint_as_float(u0 & 0xffff0000u);
        ax1 += v1 * __uint_as_float(u1 << 16);
        ay1 += v1 * __uint_as_float(u1 & 0xffff0000u);
    }
    if (e < end) {
        int2 p0 = epair[e];
        unsigned u0 = *(const unsigned*)(tmpb + (size_t)p0.x * D + lane * 2);
        float v0 = __int_as_float(p0.y);
        ax0 += v0 * __uint_as_float(u0 << 16);
        ay0 += v0 * __uint_as_float(u0 & 0xffff0000u);
    }
    float2* o = (float2*)(out + (size_t)wave * D + lane * 2);
    float2 c = *o;
    c.x += ax0 + ax1;
    c.y += ay0 + ay1;
    *o = c;
}

extern "C" void kernel_launch(void* const* d_in, const int* in_sizes, int n_in,
                              void* d_out, int out_size, void* d_ws, size_t ws_size,
                              hipStream_t stream) {
    const float* h     = (const float*)d_in[0];
    const float* eval_ = (const float*)d_in[1];
    const float* Wself = (const float*)d_in[2];
    const float* bself = (const float*)d_in[3];
    const float* Wnb   = (const float*)d_in[4];
    const float* bnb   = (const float*)d_in[5];
    const int*   erow  = (const int*)d_in[6];
    const int*   ecol  = (const int*)d_in[7];
    float* out = (float*)d_out;

    // ws layout (bytes):
    // tmpb:   NN_PAD*D*2            = 25,608,192
    // epair:  NE*8                  = 12,800,000
    // wcat:   256*128*2             = 65,536
    // counts/offsets/cursor/bsum/bscan ints
    char* p = (char*)d_ws;
    __bf16* tmpb  = (__bf16*)p;                 p += (size_t)NN_PAD * D * 2;
    int2*   epair = (int2*)p;                   p += (size_t)NE * 8;
    __bf16* wcat  = (__bf16*)p;                 p += 256 * 128 * 2;
    int* counts   = (int*)p;                    p += (size_t)NN * 4;
    int* offsets  = (int*)p;                    p += (size_t)(NN + 1) * 4;
    int* cursor   = (int*)p;                    p += (size_t)NN * 4;
    int* bsum     = (int*)p;                    p += (size_t)NB * 4;
    int* bscan    = (int*)p;

    hipMemsetAsync(counts, 0, (size_t)NN * 4, stream);

    w_convert<<<128, 256, 0, stream>>>(Wself, Wnb, wcat);
    gemm_mfma<<<NN_PAD / 64, 256, 0, stream>>>(h, wcat, bself, bnb, out, tmpb);

    histogram<<<(NE + 255) / 256, 256, 0, stream>>>(erow, counts);
    block_sums<<<NB, 256, 0, stream>>>(counts, bsum);
    scan_bsums<<<1, 512, 0, stream>>>(bsum, bscan, offsets);
    scan_local<<<NB, 256, 0, stream>>>(counts, bscan, offsets, cursor);
    scatter_csr<<<(NE + 255) / 256, 256, 0, stream>>>(erow, ecol, eval_, cursor, epair);
    aggregate<<<(NN * 64) / 256, 256, 0, stream>>>(tmpb, offsets, epair, out);
}